// Round 9
// baseline (105.069 us; speedup 1.0000x reference)
//
#include <hip/hip_runtime.h>

// Problem constants (from reference): B=4096, N_IN=64, N_OUT=64, M=4096.
#define BATCH 4096
#define NIN   64
#define NOUT  64
#define M_TOT (NIN * NOUT)

// ---------------------------------------------------------------------------
// Kernel 1: build WM from (aW, uW, tW). One thread per m = j*64 + k.
// Transposed layout for coalesced main-kernel loads:
//   WT[(j*3 + q)*64 + k] = row q of matrix (j,k)  (quad = (Rq0,Rq1,Rq2,tq))
// bottom row [0,0,0,1] implicit. 192 KiB in d_ws.
// ---------------------------------------------------------------------------
__global__ __launch_bounds__(256) void build_wm_kernel(
    const float* __restrict__ aW, const float* __restrict__ uW,
    const float* __restrict__ tW, float4* __restrict__ WT) {
  int m = blockIdx.x * 256 + threadIdx.x;
  if (m >= M_TOT) return;
  int j = m >> 6, k = m & 63;

  float a  = aW[m];
  float ux = 1.f / (1.f + expf(-uW[3 * m + 0]));
  float uy = 1.f / (1.f + expf(-uW[3 * m + 1]));
  float uz = 1.f / (1.f + expf(-uW[3 * m + 2]));
  float inv = 1.f / sqrtf(ux * ux + uy * uy + uz * uz);
  ux *= inv; uy *= inv; uz *= inv;

  float sa = sinf(a), ca = cosf(a);
  float xx = ux * ux, yy = uy * uy, zz = uz * uz;
  float xy = ux * uy, xz = ux * uz, yz = uy * uz;

  float R00 = ca * (1.f - xx) + xx;
  float R01 = -sa * uz + ca * (-xy) + xy;
  float R02 =  sa * uy + ca * (-xz) + xz;
  float R10 =  sa * uz + ca * (-xy) + xy;
  float R11 = ca * (1.f - yy) + yy;
  float R12 = -sa * ux + ca * (-yz) + yz;
  float R20 = -sa * uy + ca * (-xz) + xz;
  float R21 =  sa * ux + ca * (-yz) + yz;
  float R22 = ca * (1.f - zz) + zz;

  float t0 = tW[3 * m + 0], t1 = tW[3 * m + 1], t2 = tW[3 * m + 2];

  WT[(j * 3 + 0) * 64 + k] = make_float4(R00, R01, R02, t0);
  WT[(j * 3 + 1) * 64 + k] = make_float4(R10, R11, R12, t1);
  WT[(j * 3 + 2) * 64 + k] = make_float4(R20, R21, R22, t2);
}

// ---------------------------------------------------------------------------
// Kernel 2: chain product, 4-way j-split; I distributed across lanes.
// Block = 256 threads = 4 waves, one batch row b = blockIdx.x:
//   wave wq: j in [16wq, 16wq+16) -> partial product P_wq
// I-slice per wave = 16 j x 4 rows = EXACTLY 64 float4: lane l owns
// I4[base + l] = row (l&3) of step (l>>2), fetched with ONE coalesced
// per-lane dwordx4 (HBM latency paid once per wave, not per j). In the
// fully-unrolled 16-step loop, I rows are broadcast via v_readlane with
// compile-time lane indices -> VALU pipe, zero latency, zero LDS traffic
// (round 6 showed per-j ds_read saturates the CU's LDS pipe; rounds 5-8
// showed s_load I-latency stalls ~40% of cycles regardless of TLP/ILP).
// W loads lane-coalesced (1 KiB/instr), L1/L2-resident.
// Combine O = (P0@P1)@(P2@P3): two-level tree via padded LDS.
// NO register cap (round-2 lesson: forced VGPR=32 -> 200MB scratch spill).
// ---------------------------------------------------------------------------

#define RLF(v, L) __int_as_float(__builtin_amdgcn_readlane(__float_as_int(v), (L)))

// fold full 4x4 A (A00..A33) into carry c: c = c @ A
#define CMUL_ROW(x)                                                            \
  {                                                                            \
    float t0 = c[x*4+0]*A00 + c[x*4+1]*A10 + c[x*4+2]*A20 + c[x*4+3]*A30;      \
    float t1 = c[x*4+0]*A01 + c[x*4+1]*A11 + c[x*4+2]*A21 + c[x*4+3]*A31;      \
    float t2 = c[x*4+0]*A02 + c[x*4+1]*A12 + c[x*4+2]*A22 + c[x*4+3]*A32;      \
    float t3 = c[x*4+0]*A03 + c[x*4+1]*A13 + c[x*4+2]*A23 + c[x*4+3]*A33;      \
    c[x*4+0] = t0; c[x*4+1] = t1; c[x*4+2] = t2; c[x*4+3] = t3;                \
  }

// load full 4x4 A from LDS row q, fold into c
#define LDS_FOLD(q)                                                            \
  {                                                                            \
    float A00 = P[q][lane][0],  A01 = P[q][lane][1];                           \
    float A02 = P[q][lane][2],  A03 = P[q][lane][3];                           \
    float A10 = P[q][lane][4],  A11 = P[q][lane][5];                           \
    float A12 = P[q][lane][6],  A13 = P[q][lane][7];                           \
    float A20 = P[q][lane][8],  A21 = P[q][lane][9];                           \
    float A22 = P[q][lane][10], A23 = P[q][lane][11];                          \
    float A30 = P[q][lane][12], A31 = P[q][lane][13];                          \
    float A32 = P[q][lane][14], A33 = P[q][lane][15];                          \
    CMUL_ROW(0) CMUL_ROW(1) CMUL_ROW(2) CMUL_ROW(3)                            \
  }

__global__ __launch_bounds__(256) void chain_kernel(
    const float4* __restrict__ I4, const float4* __restrict__ WT,
    float4* __restrict__ O4) {
  const int lane = threadIdx.x & 63;
  const int wq   = threadIdx.x >> 6;  // wave's j-quarter: [16*wq, 16*wq+16)
  const int b    = (int)blockIdx.x;

  // ONE coalesced per-lane load: lane l holds I row (l&3) of step (l>>2)
  const float4 myI = I4[(size_t)(b * NIN + wq * 16) * 4 + lane];
  const float4* __restrict__ Wb = WT + (size_t)(wq * 16 * 3) * 64 + lane;

  float c[16];

#pragma unroll
  for (int j = 0; j < 16; ++j) {
    float4 w0 = Wb[j * 192], w1 = Wb[j * 192 + 64], w2 = Wb[j * 192 + 128];

    // broadcast I rows of step j from owning lanes (compile-time indices)
    float r0x = RLF(myI.x, 4*j+0), r0y = RLF(myI.y, 4*j+0),
          r0z = RLF(myI.z, 4*j+0), r0w = RLF(myI.w, 4*j+0);
    float r1x = RLF(myI.x, 4*j+1), r1y = RLF(myI.y, 4*j+1),
          r1z = RLF(myI.z, 4*j+1), r1w = RLF(myI.w, 4*j+1);
    float r2x = RLF(myI.x, 4*j+2), r2y = RLF(myI.y, 4*j+2),
          r2z = RLF(myI.z, 4*j+2), r2w = RLF(myI.w, 4*j+2);
    float r3x = RLF(myI.x, 4*j+3), r3y = RLF(myI.y, 4*j+3),
          r3z = RLF(myI.z, 4*j+3), r3w = RLF(myI.w, 4*j+3);

    // A = I[j] @ W (W bottom row = [0,0,0,1])
    float A00 = r0x*w0.x + r0y*w1.x + r0z*w2.x;
    float A01 = r0x*w0.y + r0y*w1.y + r0z*w2.y;
    float A02 = r0x*w0.z + r0y*w1.z + r0z*w2.z;
    float A03 = r0x*w0.w + r0y*w1.w + r0z*w2.w + r0w;
    float A10 = r1x*w0.x + r1y*w1.x + r1z*w2.x;
    float A11 = r1x*w0.y + r1y*w1.y + r1z*w2.y;
    float A12 = r1x*w0.z + r1y*w1.z + r1z*w2.z;
    float A13 = r1x*w0.w + r1y*w1.w + r1z*w2.w + r1w;
    float A20 = r2x*w0.x + r2y*w1.x + r2z*w2.x;
    float A21 = r2x*w0.y + r2y*w1.y + r2z*w2.y;
    float A22 = r2x*w0.z + r2y*w1.z + r2z*w2.z;
    float A23 = r2x*w0.w + r2y*w1.w + r2z*w2.w + r2w;
    float A30 = r3x*w0.x + r3y*w1.x + r3z*w2.x;
    float A31 = r3x*w0.y + r3y*w1.y + r3z*w2.y;
    float A32 = r3x*w0.z + r3y*w1.z + r3z*w2.z;
    float A33 = r3x*w0.w + r3y*w1.w + r3z*w2.w + r3w;

    if (j == 0) {
      c[0]=A00;  c[1]=A01;  c[2]=A02;  c[3]=A03;
      c[4]=A10;  c[5]=A11;  c[6]=A12;  c[7]=A13;
      c[8]=A20;  c[9]=A21;  c[10]=A22; c[11]=A23;
      c[12]=A30; c[13]=A31; c[14]=A32; c[15]=A33;
    } else {
      CMUL_ROW(0) CMUL_ROW(1) CMUL_ROW(2) CMUL_ROW(3)
    }
  }

  // combine: O = (P0 @ P1) @ (P2 @ P3), two-level tree
  // LDS slots: 0 <- P1, 1 <- P3, 2 <- P2@P3
  __shared__ float P[3][64][17];  // padded stride 17 -> conflict-free
  if (wq == 1) {
#pragma unroll
    for (int i = 0; i < 16; i++) P[0][lane][i] = c[i];
  }
  if (wq == 3) {
#pragma unroll
    for (int i = 0; i < 16; i++) P[1][lane][i] = c[i];
  }
  __syncthreads();
  if (wq == 0) { LDS_FOLD(0) }  // c = P0 @ P1
  if (wq == 2) {
    LDS_FOLD(1)                 // c = P2 @ P3
#pragma unroll
    for (int i = 0; i < 16; i++) P[2][lane][i] = c[i];
  }
  __syncthreads();
  if (wq == 0) {
    LDS_FOLD(2)                 // c = (P0@P1) @ (P2@P3)

    float4* o = O4 + ((size_t)b * NOUT + lane) * 4;
    o[0] = make_float4(c[0],  c[1],  c[2],  c[3]);
    o[1] = make_float4(c[4],  c[5],  c[6],  c[7]);
    o[2] = make_float4(c[8],  c[9],  c[10], c[11]);
    o[3] = make_float4(c[12], c[13], c[14], c[15]);
  }
}

extern "C" void kernel_launch(void* const* d_in, const int* in_sizes, int n_in,
                              void* d_out, int out_size, void* d_ws, size_t ws_size,
                              hipStream_t stream) {
  const float* I  = (const float*)d_in[0];
  const float* aW = (const float*)d_in[1];
  const float* uW = (const float*)d_in[2];
  const float* tW = (const float*)d_in[3];

  float4* WT = (float4*)d_ws;  // 192 KiB scratch for transposed WM

  build_wm_kernel<<<M_TOT / 256, 256, 0, stream>>>(aW, uW, tW, WT);
  chain_kernel<<<BATCH, 256, 0, stream>>>((const float4*)I, WT, (float4*)d_out);
}

// Round 10
// 58.223 us; speedup vs baseline: 1.8046x; 1.8046x over previous
//
#include <hip/hip_runtime.h>

// Problem constants (from reference): B=4096, N_IN=64, N_OUT=64, M=4096.
#define BATCH 4096
#define NIN   64
#define NOUT  64
#define M_TOT (NIN * NOUT)

// ---------------------------------------------------------------------------
// Kernel 1: build WM from (aW, uW, tW). One thread per m = j*64 + k.
// Transposed layout for coalesced main-kernel loads:
//   WT[(j*3 + q)*64 + k] = row q of matrix (j,k)  (quad = (Rq0,Rq1,Rq2,tq))
// bottom row [0,0,0,1] implicit. 192 KiB in d_ws.
// ---------------------------------------------------------------------------
__global__ __launch_bounds__(256) void build_wm_kernel(
    const float* __restrict__ aW, const float* __restrict__ uW,
    const float* __restrict__ tW, float4* __restrict__ WT) {
  int m = blockIdx.x * 256 + threadIdx.x;
  if (m >= M_TOT) return;
  int j = m >> 6, k = m & 63;

  float a  = aW[m];
  float ux = 1.f / (1.f + expf(-uW[3 * m + 0]));
  float uy = 1.f / (1.f + expf(-uW[3 * m + 1]));
  float uz = 1.f / (1.f + expf(-uW[3 * m + 2]));
  float inv = 1.f / sqrtf(ux * ux + uy * uy + uz * uz);
  ux *= inv; uy *= inv; uz *= inv;

  float sa = sinf(a), ca = cosf(a);
  float xx = ux * ux, yy = uy * uy, zz = uz * uz;
  float xy = ux * uy, xz = ux * uz, yz = uy * uz;

  float R00 = ca * (1.f - xx) + xx;
  float R01 = -sa * uz + ca * (-xy) + xy;
  float R02 =  sa * uy + ca * (-xz) + xz;
  float R10 =  sa * uz + ca * (-xy) + xy;
  float R11 = ca * (1.f - yy) + yy;
  float R12 = -sa * ux + ca * (-yz) + yz;
  float R20 = -sa * uy + ca * (-xz) + xz;
  float R21 =  sa * ux + ca * (-yz) + yz;
  float R22 = ca * (1.f - zz) + zz;

  float t0 = tW[3 * m + 0], t1 = tW[3 * m + 1], t2 = tW[3 * m + 2];

  WT[(j * 3 + 0) * 64 + k] = make_float4(R00, R01, R02, t0);
  WT[(j * 3 + 1) * 64 + k] = make_float4(R10, R11, R12, t1);
  WT[(j * 3 + 2) * 64 + k] = make_float4(R20, R21, R22, t2);
}

// ---------------------------------------------------------------------------
// Kernel 2: chain product; 2-way j-split x 2 batch rows per thread.
// Block = 128 threads = 2 waves; block handles b0=2*blk, b1=b0+1:
//   wave 0: j in [0,32) for both b's; wave 1: j in [32,64).
// NEW (round 10): I rows come through an explicit register DOUBLE-BUFFER
// of vector loads (global_load_dwordx4, wave-uniform address): buffer for
// even j reloaded right after its consumption while the odd-j step computes
// (issue-to-use ~464 cyc), halving the exposed ~900cy HBM latency that
// rounds 5-9 showed to be the dominant stall (VALUBusy 52-60% with no
// BW/occupancy limit; R9 proved removing I-latency shifts busy to 72+%).
// W loads stay lane-coalesced VMEM (L2-resident, covered by unroll).
// __launch_bounds__(128,4): VGPR cap 128 -> 4 waves/SIMD = 8 blocks/CU =
// exactly one dispatch round for grid 2048. Combine O = P0@P1 via LDS.
// ---------------------------------------------------------------------------

// write A-row (4 dests) from I-row r and affine W rows W0..W2
#define IMUL_TO(D0, D1, D2, D3, r, W0, W1, W2)                       \
  D0 = r.x * W0.x + r.y * W1.x + r.z * W2.x;                         \
  D1 = r.x * W0.y + r.y * W1.y + r.z * W2.y;                         \
  D2 = r.x * W0.z + r.y * W1.z + r.z * W2.z;                         \
  D3 = r.x * W0.w + r.y * W1.w + r.z * W2.w + r.w;

// fold A (A00..A33) into carry array cc
#define CMUL_ROW_G(cc, x)                                                      \
  {                                                                            \
    float t0 = cc[x*4+0]*A00 + cc[x*4+1]*A10 + cc[x*4+2]*A20 + cc[x*4+3]*A30;  \
    float t1 = cc[x*4+0]*A01 + cc[x*4+1]*A11 + cc[x*4+2]*A21 + cc[x*4+3]*A31;  \
    float t2 = cc[x*4+0]*A02 + cc[x*4+1]*A12 + cc[x*4+2]*A22 + cc[x*4+3]*A32;  \
    float t3 = cc[x*4+0]*A03 + cc[x*4+1]*A13 + cc[x*4+2]*A23 + cc[x*4+3]*A33;  \
    cc[x*4+0] = t0; cc[x*4+1] = t1; cc[x*4+2] = t2; cc[x*4+3] = t3;            \
  }

// A = rows @ W(w0,w1,w2); cc = cc @ A
#define STEP_B(cc, R0, R1, R2, R3)                                             \
  {                                                                            \
    float A00, A01, A02, A03, A10, A11, A12, A13;                              \
    float A20, A21, A22, A23, A30, A31, A32, A33;                              \
    IMUL_TO(A00, A01, A02, A03, R0, w0, w1, w2)                                \
    IMUL_TO(A10, A11, A12, A13, R1, w0, w1, w2)                                \
    IMUL_TO(A20, A21, A22, A23, R2, w0, w1, w2)                                \
    IMUL_TO(A30, A31, A32, A33, R3, w0, w1, w2)                                \
    CMUL_ROW_G(cc, 0) CMUL_ROW_G(cc, 1) CMUL_ROW_G(cc, 2) CMUL_ROW_G(cc, 3)   \
  }

// one j-step: shared W rows, fold both b-chains from the given buffer set
#define DO_STEP(JJ, U0, U1, U2, U3, S0, S1, S2, S3)                            \
  {                                                                            \
    float4 w0 = Wb[(JJ) * 192], w1 = Wb[(JJ) * 192 + 64],                      \
           w2 = Wb[(JJ) * 192 + 128];                                          \
    STEP_B(c0, U0, U1, U2, U3)                                                 \
    STEP_B(c1, S0, S1, S2, S3)                                                 \
  }

// reload a buffer set with step JJ's I rows for both b's
#define RELOAD(U0, U1, U2, U3, S0, S1, S2, S3, JJ)                             \
  U0 = Ib0[(JJ) * 4 + 0]; U1 = Ib0[(JJ) * 4 + 1];                              \
  U2 = Ib0[(JJ) * 4 + 2]; U3 = Ib0[(JJ) * 4 + 3];                              \
  S0 = Ib1[(JJ) * 4 + 0]; S1 = Ib1[(JJ) * 4 + 1];                              \
  S2 = Ib1[(JJ) * 4 + 2]; S3 = Ib1[(JJ) * 4 + 3];

__global__ __launch_bounds__(128, 4) void chain_kernel(
    const float4* __restrict__ I4, const float4* __restrict__ WT,
    float4* __restrict__ O4) {
  const int lane = threadIdx.x & 63;
  const int half = threadIdx.x >> 6;  // 0: j in [0,32), 1: j in [32,64)
  const int b0   = (int)blockIdx.x * 2;

  const int ioff0 = __builtin_amdgcn_readfirstlane((b0 * NIN + half * 32) * 4);
  const float4* __restrict__ Ib0 = I4 + ioff0;
  const float4* __restrict__ Ib1 = Ib0 + NIN * 4;  // b1 = b0 + 1
  const float4* __restrict__ Wb  = WT + (size_t)(half * 32 * 3) * 64 + lane;

  float c0[16], c1[16];

  // register double-buffer: (u,s) = even-j rows, (v,x) = odd-j rows
  float4 u0, u1, u2, u3, s0, s1, s2, s3;
  float4 v0, v1, v2, v3, x0, x1, x2, x3;

  RELOAD(u0, u1, u2, u3, s0, s1, s2, s3, 0)
  RELOAD(v0, v1, v2, v3, x0, x1, x2, x3, 1)

  {  // peeled j=0: c = A directly (skip identity multiply)
    float4 w0 = Wb[0], w1 = Wb[64], w2 = Wb[128];
    IMUL_TO(c0[0],  c0[1],  c0[2],  c0[3],  u0, w0, w1, w2)
    IMUL_TO(c0[4],  c0[5],  c0[6],  c0[7],  u1, w0, w1, w2)
    IMUL_TO(c0[8],  c0[9],  c0[10], c0[11], u2, w0, w1, w2)
    IMUL_TO(c0[12], c0[13], c0[14], c0[15], u3, w0, w1, w2)
    IMUL_TO(c1[0],  c1[1],  c1[2],  c1[3],  s0, w0, w1, w2)
    IMUL_TO(c1[4],  c1[5],  c1[6],  c1[7],  s1, w0, w1, w2)
    IMUL_TO(c1[8],  c1[9],  c1[10], c1[11], s2, w0, w1, w2)
    IMUL_TO(c1[12], c1[13], c1[14], c1[15], s3, w0, w1, w2)
  }
  RELOAD(u0, u1, u2, u3, s0, s1, s2, s3, 2)   // issue I[2] during j=1 compute

  for (int jj = 1; jj < 29; jj += 2) {
    DO_STEP(jj, v0, v1, v2, v3, x0, x1, x2, x3)
    RELOAD(v0, v1, v2, v3, x0, x1, x2, x3, jj + 2)
    DO_STEP(jj + 1, u0, u1, u2, u3, s0, s1, s2, s3)
    RELOAD(u0, u1, u2, u3, s0, s1, s2, s3, jj + 3)
  }
  // loop covered j=1..28, issued through I[30]. Peeled tail:
  DO_STEP(29, v0, v1, v2, v3, x0, x1, x2, x3)
  RELOAD(v0, v1, v2, v3, x0, x1, x2, x3, 31)
  DO_STEP(30, u0, u1, u2, u3, s0, s1, s2, s3)
  DO_STEP(31, v0, v1, v2, v3, x0, x1, x2, x3)

  // combine: O = P0 @ P1 for both b's
  __shared__ float P[2][64][17];  // padded stride 17 -> conflict-free
  if (half == 1) {
#pragma unroll
    for (int i = 0; i < 16; i++) P[0][lane][i] = c0[i];
#pragma unroll
    for (int i = 0; i < 16; i++) P[1][lane][i] = c1[i];
  }
  __syncthreads();
  if (half == 0) {
    {
      float A00 = P[0][lane][0],  A01 = P[0][lane][1];
      float A02 = P[0][lane][2],  A03 = P[0][lane][3];
      float A10 = P[0][lane][4],  A11 = P[0][lane][5];
      float A12 = P[0][lane][6],  A13 = P[0][lane][7];
      float A20 = P[0][lane][8],  A21 = P[0][lane][9];
      float A22 = P[0][lane][10], A23 = P[0][lane][11];
      float A30 = P[0][lane][12], A31 = P[0][lane][13];
      float A32 = P[0][lane][14], A33 = P[0][lane][15];
      CMUL_ROW_G(c0, 0) CMUL_ROW_G(c0, 1) CMUL_ROW_G(c0, 2) CMUL_ROW_G(c0, 3)
      float4* o = O4 + ((size_t)b0 * NOUT + lane) * 4;
      o[0] = make_float4(c0[0],  c0[1],  c0[2],  c0[3]);
      o[1] = make_float4(c0[4],  c0[5],  c0[6],  c0[7]);
      o[2] = make_float4(c0[8],  c0[9],  c0[10], c0[11]);
      o[3] = make_float4(c0[12], c0[13], c0[14], c0[15]);
    }
    {
      float A00 = P[1][lane][0],  A01 = P[1][lane][1];
      float A02 = P[1][lane][2],  A03 = P[1][lane][3];
      float A10 = P[1][lane][4],  A11 = P[1][lane][5];
      float A12 = P[1][lane][6],  A13 = P[1][lane][7];
      float A20 = P[1][lane][8],  A21 = P[1][lane][9];
      float A22 = P[1][lane][10], A23 = P[1][lane][11];
      float A30 = P[1][lane][12], A31 = P[1][lane][13];
      float A32 = P[1][lane][14], A33 = P[1][lane][15];
      CMUL_ROW_G(c1, 0) CMUL_ROW_G(c1, 1) CMUL_ROW_G(c1, 2) CMUL_ROW_G(c1, 3)
      float4* o = O4 + ((size_t)(b0 + 1) * NOUT + lane) * 4;
      o[0] = make_float4(c1[0],  c1[1],  c1[2],  c1[3]);
      o[1] = make_float4(c1[4],  c1[5],  c1[6],  c1[7]);
      o[2] = make_float4(c1[8],  c1[9],  c1[10], c1[11]);
      o[3] = make_float4(c1[12], c1[13], c1[14], c1[15]);
    }
  }
}

extern "C" void kernel_launch(void* const* d_in, const int* in_sizes, int n_in,
                              void* d_out, int out_size, void* d_ws, size_t ws_size,
                              hipStream_t stream) {
  const float* I  = (const float*)d_in[0];
  const float* aW = (const float*)d_in[1];
  const float* uW = (const float*)d_in[2];
  const float* tW = (const float*)d_in[3];

  float4* WT = (float4*)d_ws;  // 192 KiB scratch for transposed WM

  build_wm_kernel<<<M_TOT / 256, 256, 0, stream>>>(aW, uW, tW, WT);
  chain_kernel<<<BATCH / 2, 128, 0, stream>>>((const float4*)I, WT, (float4*)d_out);
}